// Round 5
// baseline (1099.184 us; speedup 1.0000x reference)
//
#include <hip/hip_runtime.h>
#include <hip/hip_bf16.h>

// PointCloudNetPersistencePrediction — round 5: K-split skinny GEMM.
// R4 post-mortem: mfma_apply at 31us/dispatch, 2 waves/SIMD (512 blocks) ->
// latency-bound on A reads (~4.1 TB/s effective vs ~14 TB/s L3 floor of 9us).
// Fix: 4-way K-split per 16-row M-tile (block=4 waves, K chunks of 512),
// LDS partial-C reduce -> grid (128,16)=2048 blocks = 8 waves/SIMD.

#define NN 2048
#define NPAIR 16

typedef _Float16 half8 __attribute__((ext_vector_type(8)));
typedef _Float16 half4 __attribute__((ext_vector_type(4)));
typedef float f32x4 __attribute__((ext_vector_type(4)));

#define C2F 0.28853900817779268f   //  0.2 * log2(e)
#define CWF -0.14426950408889634f  // -0.1 * log2(e)

// ---- init: Xs fp32 [p][i][{x,y,z,q}]; XT fp16 [p][16][2048] (rows 3-15 = 0) ----
__global__ __launch_bounds__(256) void init_k(const float* __restrict__ pc,
                                              const float* __restrict__ alphas,
                                              float* __restrict__ Xs,
                                              _Float16* __restrict__ XT) {
    int gid = blockIdx.x * 256 + threadIdx.x;
    if (gid >= NPAIR * NN) return;
    int p = gid >> 11, i = gid & (NN - 1);
    int b = p >> 2, k = p & 3;
    const float* pcr = pc + ((size_t)b * NN + i) * 3;
    const float* al  = alphas + k * 3;
    float x = pcr[0] * al[0], y = pcr[1] * al[1], z = pcr[2] * al[2];
    float4 o; o.x = x; o.y = y; o.z = z; o.w = CWF * (x * x + y * y + z * z);
    ((float4*)Xs)[gid] = o;
    _Float16* xt = XT + (size_t)p * 16 * NN + i;
    xt[0 * NN] = (_Float16)x;
    xt[1 * NN] = (_Float16)y;
    xt[2 * NN] = (_Float16)z;
#pragma unroll
    for (int n = 3; n < 16; ++n) xt[n * NN] = (_Float16)0.f;
}

__device__ __forceinline__ float wfun(float4 xi, float4 xj) {
    float dot = xi.x * xj.x + xi.y * xj.y + xi.z * xj.z;
    float w = __builtin_amdgcn_exp2f((xi.w + xj.w) + C2F * dot);
    return (w < 0.1f) ? 0.0f : w;
}

// ---- deg: ihd[p][i] = 0.5 / deg (R3 structure, LDS-staged xj) ----
__global__ __launch_bounds__(1024, 4) void deg_k(const float* __restrict__ Xs,
                                                 float* __restrict__ ihd) {
    __shared__ __align__(16) float smem[4096];
    const int p    = blockIdx.y;
    const int tid  = threadIdx.x;
    const int lane = tid & 63;
    const int wv   = tid >> 6;
    const int rA   = blockIdx.x * 128 + lane;
    const int rB   = rA + 64;
    const float* Xp = Xs + (size_t)p * NN * 4;
    float4 xiA = *(const float4*)(Xp + rA * 4);
    float4 xiB = *(const float4*)(Xp + rB * 4);
    float sA = 0.f, sB = 0.f;
    float* stw = smem + wv * 256;
    const int jch = wv * 128;
    float4 v = *(const float4*)(Xp + (jch + lane) * 4);
    for (int jt = 0; jt < 2; ++jt) {
        *(float4*)(stw + lane * 4) = v;
        if (jt == 0) v = *(const float4*)(Xp + (jch + 64 + lane) * 4);
        __builtin_amdgcn_wave_barrier();
#pragma unroll 8
        for (int jj = 0; jj < 64; ++jj) {
            float4 xj = *(const float4*)(stw + jj * 4);
            sA += wfun(xiA, xj);
            sB += wfun(xiB, xj);
        }
        __builtin_amdgcn_wave_barrier();
    }
    __syncthreads();
    smem[wv * 128 + lane]      = sA;
    smem[wv * 128 + 64 + lane] = sB;
    __syncthreads();
    if (tid < 128) {
        float d = 0.f;
#pragma unroll
        for (int w = 0; w < 16; ++w) d += smem[w * 128 + tid];
        ihd[p * NN + blockIdx.x * 128 + tid] = 0.5f / d;
    }
}

// ---- build A fp16 [g][2048][2048]: A[i][j] = ihd[i]*w(i,j), diag = 0.5+ihd ----
__global__ __launch_bounds__(1024) void buildA_k(const float* __restrict__ Xs,
                                                 const float* __restrict__ ihd,
                                                 _Float16* __restrict__ A, int pair0) {
    int g = blockIdx.y, p = pair0 + g;
    int wv = threadIdx.x >> 6, lane = threadIdx.x & 63;
    const float4* Xp = (const float4*)(Xs + (size_t)p * NN * 4);
    _Float16* Ag = A + (size_t)g * NN * NN;
    int row0 = blockIdx.x * 128 + wv * 8;
    for (int rr = 0; rr < 8; ++rr) {
        int row = row0 + rr;
        float4 xi = Xp[row];
        float ih = ihd[p * NN + row];
        float dia = 0.5f + ih;
        for (int jc = 0; jc < NN; jc += 64) {
            int j = jc + lane;
            float4 xj = Xp[j];
            float dot = xi.x * xj.x + xi.y * xj.y + xi.z * xj.z;
            float w = __builtin_amdgcn_exp2f((xi.w + xj.w) + C2F * dot);
            float a = (w < 0.1f) ? 0.f : (ih * w);
            if (j == row) a = dia;
            Ag[(size_t)row * NN + j] = (_Float16)a;
        }
    }
}

// ---- apply: Ct[16][2048] = (A @ Bt^T)^T, 4-way K-split + LDS reduce ----
// block = 4 waves on one 16-row M-tile; wave wv covers K in [wv*512, wv*512+512).
__global__ __launch_bounds__(256, 8) void mfma_apply_k(const _Float16* __restrict__ A,
                                                       const _Float16* __restrict__ Bt,
                                                       _Float16* __restrict__ Ct,
                                                       float* __restrict__ lvl,
                                                       int t, int pair0) {
    __shared__ float red[4][256];
    const int tid  = threadIdx.x;
    const int lane = tid & 63;
    const int wv   = tid >> 6;
    const int g = blockIdx.y, p = pair0 + g;
    const int m0 = blockIdx.x * 16;
    const int idx16 = lane & 15, quad = lane >> 4;
    const _Float16* ap = A  + (size_t)g * NN * NN + (size_t)(m0 + idx16) * NN
                            + wv * 512 + quad * 8;
    const _Float16* bp = Bt + ((size_t)p * 16 + idx16) * NN + wv * 512 + quad * 8;
    f32x4 acc0 = {0.f, 0.f, 0.f, 0.f}, acc1 = {0.f, 0.f, 0.f, 0.f};
#pragma unroll
    for (int ks = 0; ks < 16; ks += 2) {
        half8 a0 = *(const half8*)(ap + ks * 32);
        half8 b0 = *(const half8*)(bp + ks * 32);
        acc0 = __builtin_amdgcn_mfma_f32_16x16x32_f16(a0, b0, acc0, 0, 0, 0);
        half8 a1 = *(const half8*)(ap + ks * 32 + 32);
        half8 b1 = *(const half8*)(bp + ks * 32 + 32);
        acc1 = __builtin_amdgcn_mfma_f32_16x16x32_f16(a1, b1, acc1, 0, 0, 0);
    }
    f32x4 acc = acc0 + acc1;
    *(f32x4*)&red[wv][lane * 4] = acc;
    __syncthreads();
    // thread tid -> C element (row = tid&15, col = tid>>4)
    const int col = tid >> 4, row = tid & 15;
    const int idx = (row >> 2) * 64 + col * 4 + (row & 3);
    float s = red[0][idx] + red[1][idx] + red[2][idx] + red[3][idx];
    const int m = m0 + row;
    Ct[((size_t)p * 16 + col) * NN + m] = (_Float16)s;
    if (lvl) lvl[(((size_t)p * 5 + t) * 16 + col) * NN + m] = s;
}

// ---- build UT fp16 [p][16][2048]: rows 0-11 = |psi_0..3 X|, 12-15 = 0 ----
__global__ __launch_bounds__(256) void buildU_k(const float* __restrict__ Xs,
                                                const float* __restrict__ LT1,
                                                _Float16* __restrict__ UT, int pair0) {
    int g = blockIdx.y, p = pair0 + g;
    int m = blockIdx.x * 256 + threadIdx.x;
    const float* lp = LT1 + (size_t)p * 5 * 16 * NN;
    float4 xr = ((const float4*)Xs)[p * NN + m];
    float prev[3] = {xr.x, xr.y, xr.z};
    _Float16* ut = UT + (size_t)p * 16 * NN + m;
#pragma unroll
    for (int jw = 0; jw < 4; ++jw) {
#pragma unroll
        for (int c = 0; c < 3; ++c) {
            float nx = lp[((size_t)jw * 16 + c) * NN + m];
            ut[(3 * jw + c) * NN] = (_Float16)fabsf(prev[c] - nx);
            prev[c] = nx;
        }
    }
#pragma unroll
    for (int n = 12; n < 16; ++n) ut[n * NN] = (_Float16)0.f;
}

// ---- final mean over N of 48 features (levels [p][t][n][m]) ----
__global__ __launch_bounds__(64) void reduce_k(const float* __restrict__ Xs,
                                               const float* __restrict__ LT1,
                                               const float* __restrict__ LT2,
                                               float* __restrict__ out) {
    int f = blockIdx.x, p = blockIdx.y, lane = threadIdx.x;
    const float* l1 = LT1 + (size_t)p * 5 * 16 * NN;
    const float* l2 = LT2 + (size_t)p * 5 * 16 * NN;
    float s = 0.f;
    for (int m = lane; m < NN; m += 64) {
        float v;
        if (f < 3) {
            v = l1[((size_t)4 * 16 + f) * NN + m];
        } else if (f < 18) {
            int j = (f - 3) / 3, c = (f - 3) % 3;
            float a = (j == 0) ? Xs[((size_t)p * NN + m) * 4 + c]
                               : l1[((size_t)(j - 1) * 16 + c) * NN + m];
            float b = l1[((size_t)j * 16 + c) * NN + m];
            v = fabsf(a - b);
        } else {
            int gg = f - 18, j2, uc;
            if (gg < 3)       { j2 = 1; uc = gg; }
            else if (gg < 9)  { j2 = 2; uc = gg - 3; }
            else if (gg < 18) { j2 = 3; uc = gg - 9; }
            else              { j2 = 4; uc = gg - 18; }
            v = fabsf(l2[((size_t)(j2 - 1) * 16 + uc) * NN + m]
                    - l2[((size_t)j2 * 16 + uc) * NN + m]);
        }
        s += v;
    }
#pragma unroll
    for (int off = 32; off > 0; off >>= 1) s += __shfl_down(s, off, 64);
    if (lane == 0) out[p * 48 + f] = s * (1.0f / NN);
}

extern "C" void kernel_launch(void* const* d_in, const int* in_sizes, int n_in,
                              void* d_out, int out_size, void* d_ws, size_t ws_size,
                              hipStream_t stream) {
    const float* pc     = (const float*)d_in[0];
    const float* alphas = (const float*)d_in[1];
    float* outp = (float*)d_out;

    char* base = (char*)d_ws;
    size_t off = 0;
    auto carve = [&](size_t bytes) -> void* {
        void* r = base + off;
        off = (off + bytes + 255) & ~(size_t)255;
        return r;
    };
    float*     Xs  = (float*)carve((size_t)NPAIR * NN * 4 * sizeof(float));
    float*     ihd = (float*)carve((size_t)NPAIR * NN * sizeof(float));
    _Float16*  XT  = (_Float16*)carve((size_t)NPAIR * 16 * NN * 2);
    _Float16*  UT  = (_Float16*)carve((size_t)NPAIR * 16 * NN * 2);
    _Float16*  pA  = (_Float16*)carve((size_t)NPAIR * 16 * NN * 2);
    _Float16*  pB  = (_Float16*)carve((size_t)NPAIR * 16 * NN * 2);
    float*     LT1 = (float*)carve((size_t)NPAIR * 5 * 16 * NN * sizeof(float));
    float*     LT2 = (float*)carve((size_t)NPAIR * 5 * 16 * NN * sizeof(float));
    size_t fixed = off;
    size_t Aper = (size_t)NN * NN * 2;       // 8 MB fp16 per pair
    int G = 16;
    while (G > 1 && fixed + (size_t)G * Aper > ws_size) G >>= 1;
    _Float16* A = (_Float16*)carve((size_t)G * Aper);

    init_k<<<dim3((NPAIR * NN) / 256), 256, 0, stream>>>(pc, alphas, Xs, XT);
    deg_k<<<dim3(NN / 128, NPAIR), 1024, 0, stream>>>(Xs, ihd);

    for (int p0 = 0; p0 < NPAIR; p0 += G) {
        buildA_k<<<dim3(NN / 128, G), 1024, 0, stream>>>(Xs, ihd, A, p0);

        // bank 1: B = XT
        {
            const _Float16* cur = XT;
            int slot = 0;
            for (int step = 1; step <= 16; ++step) {
                bool sv = (step == 1 || step == 2 || step == 4 || step == 8 || step == 16);
                _Float16* o = (cur == pA) ? pB : pA;
                mfma_apply_k<<<dim3(NN / 16, G), 256, 0, stream>>>(
                    A, cur, o, sv ? LT1 : nullptr, slot, p0);
                if (sv) ++slot;
                cur = o;
            }
        }

        buildU_k<<<dim3(NN / 256, G), 256, 0, stream>>>(Xs, LT1, UT, p0);

        // bank 2: B = UT
        {
            const _Float16* cur = UT;
            int slot = 0;
            for (int step = 1; step <= 16; ++step) {
                bool sv = (step == 1 || step == 2 || step == 4 || step == 8 || step == 16);
                _Float16* o = (cur == pA) ? pB : pA;
                mfma_apply_k<<<dim3(NN / 16, G), 256, 0, stream>>>(
                    A, cur, o, sv ? LT2 : nullptr, slot, p0);
                if (sv) ++slot;
                cur = o;
            }
        }
    }

    reduce_k<<<dim3(48, NPAIR), 64, 0, stream>>>(Xs, LT1, LT2, outp);
}

// Round 6
// 942.622 us; speedup vs baseline: 1.1661x; 1.1661x over previous
//
#include <hip/hip_runtime.h>
#include <hip/hip_bf16.h>

// PointCloudNetPersistencePrediction — round 6: fused W-recompute -> MFMA.
// R5 post-mortem: materialized-A applies are BW-bound streaming 128 MB of A
// per apply (~4.1 TB/s plateau; occupancy 4x change was flat). Fix: never
// materialize A. Each lane computes its 8 MFMA A-fragment values in registers
// (w = exp2(xi.w+xj.w+C2F*dot), fp16 pack), X staged in LDS (32 KB/pair).
// Per-apply global traffic 256 MB -> ~17 MB; cost -> ~8 VALU/eval, MFMA free.

#define NN 2048
#define NPAIR 16

typedef _Float16 half8 __attribute__((ext_vector_type(8)));
typedef float f32x4 __attribute__((ext_vector_type(4)));

#define C2F 0.28853900817779268f   //  0.2 * log2(e)
#define CWF -0.14426950408889634f  // -0.1 * log2(e)

// ---- init: Xs fp32 [p][i][{x,y,z,q}]; XT fp16 [p][16][2048] (rows 3-15 = 0) ----
__global__ __launch_bounds__(256) void init_k(const float* __restrict__ pc,
                                              const float* __restrict__ alphas,
                                              float* __restrict__ Xs,
                                              _Float16* __restrict__ XT) {
    int gid = blockIdx.x * 256 + threadIdx.x;
    if (gid >= NPAIR * NN) return;
    int p = gid >> 11, i = gid & (NN - 1);
    int b = p >> 2, k = p & 3;
    const float* pcr = pc + ((size_t)b * NN + i) * 3;
    const float* al  = alphas + k * 3;
    float x = pcr[0] * al[0], y = pcr[1] * al[1], z = pcr[2] * al[2];
    float4 o; o.x = x; o.y = y; o.z = z; o.w = CWF * (x * x + y * y + z * z);
    ((float4*)Xs)[gid] = o;
    _Float16* xt = XT + (size_t)p * 16 * NN + i;
    xt[0 * NN] = (_Float16)x;
    xt[1 * NN] = (_Float16)y;
    xt[2 * NN] = (_Float16)z;
#pragma unroll
    for (int n = 3; n < 16; ++n) xt[n * NN] = (_Float16)0.f;
}

__device__ __forceinline__ float wfun(float4 xi, float4 xj) {
    float dot = xi.x * xj.x + xi.y * xj.y + xi.z * xj.z;
    float w = __builtin_amdgcn_exp2f((xi.w + xj.w) + C2F * dot);
    return (w < 0.1f) ? 0.0f : w;
}

// ---- deg: ihd[p][i] = 0.5 / deg (LDS-staged xj, R3 structure) ----
__global__ __launch_bounds__(1024, 4) void deg_k(const float* __restrict__ Xs,
                                                 float* __restrict__ ihd) {
    __shared__ __align__(16) float smem[4096];
    const int p    = blockIdx.y;
    const int tid  = threadIdx.x;
    const int lane = tid & 63;
    const int wv   = tid >> 6;
    const int rA   = blockIdx.x * 128 + lane;
    const int rB   = rA + 64;
    const float* Xp = Xs + (size_t)p * NN * 4;
    float4 xiA = *(const float4*)(Xp + rA * 4);
    float4 xiB = *(const float4*)(Xp + rB * 4);
    float sA = 0.f, sB = 0.f;
    float* stw = smem + wv * 256;
    const int jch = wv * 128;
    float4 v = *(const float4*)(Xp + (jch + lane) * 4);
    for (int jt = 0; jt < 2; ++jt) {
        *(float4*)(stw + lane * 4) = v;
        if (jt == 0) v = *(const float4*)(Xp + (jch + 64 + lane) * 4);
        __builtin_amdgcn_wave_barrier();
#pragma unroll 8
        for (int jj = 0; jj < 64; ++jj) {
            float4 xj = *(const float4*)(stw + jj * 4);
            sA += wfun(xiA, xj);
            sB += wfun(xiB, xj);
        }
        __builtin_amdgcn_wave_barrier();
    }
    __syncthreads();
    smem[wv * 128 + lane]      = sA;
    smem[wv * 128 + 64 + lane] = sB;
    __syncthreads();
    if (tid < 128) {
        float d = 0.f;
#pragma unroll
        for (int w = 0; w < 16; ++w) d += smem[w * 128 + tid];
        ihd[p * NN + blockIdx.x * 128 + tid] = 0.5f / d;
    }
}

// ---- fused apply: Ct = f16( 0.5*Bt + ihd (x) (W @ Bt^T)^T ), W recomputed ----
// block = 1024 thr = 16 waves; M = 128 rows; wave wv covers K chunk [wv*128,+128).
// Lane builds A-frag (8 w values, row m0+s*16+(lane&15), k = kb+quad*8+j) in
// registers -> fp16 -> mfma 16x16x32 with B-frag from global (L2-resident).
__global__ __launch_bounds__(1024, 4) void fused_apply_k(const float* __restrict__ Xs,
                                                         const float* __restrict__ ihd,
                                                         const _Float16* __restrict__ Bt,
                                                         _Float16* __restrict__ Ct,
                                                         float* __restrict__ lvl,
                                                         int t) {
    __shared__ __align__(16) float Xlds[NN * 4];   // 32 KB: whole pair X
    __shared__ float red[16][256];                 // 16 KB: C partial reduce
    const int tid  = threadIdx.x;
    const int lane = tid & 63;
    const int wv   = tid >> 6;
    const int p    = blockIdx.y;
    const int m0   = blockIdx.x * 128;
    const int idx16 = lane & 15, quad = lane >> 4;

    // stage X[p] into LDS (coalesced, 2 float4/thread)
    {
        const float4* src = (const float4*)(Xs + (size_t)p * NN * 4);
        float4* dst = (float4*)Xlds;
        dst[tid]        = src[tid];
        dst[tid + 1024] = src[tid + 1024];
    }
    __syncthreads();

    // per-lane row data (registers, fixed for whole kernel)
    float4 xi[8];
#pragma unroll
    for (int s = 0; s < 8; ++s) xi[s] = ((const float4*)Xlds)[m0 + s * 16 + idx16];

    const _Float16* bp = Bt + ((size_t)p * 16 + idx16) * NN;
    f32x4 acc[8];
#pragma unroll
    for (int s = 0; s < 8; ++s) acc[s] = (f32x4){0.f, 0.f, 0.f, 0.f};

    for (int kc = 0; kc < 4; ++kc) {               // rolled: keep I-cache small
        const int kb = wv * 128 + kc * 32 + quad * 8;
        float4 xj[8];
#pragma unroll
        for (int j = 0; j < 8; ++j) xj[j] = ((const float4*)Xlds)[kb + j];
        half8 bf = *(const half8*)(bp + kb);
#pragma unroll
        for (int s = 0; s < 8; ++s) {
            half8 af;
#pragma unroll
            for (int j = 0; j < 8; ++j) af[j] = (_Float16)wfun(xi[s], xj[j]);
            acc[s] = __builtin_amdgcn_mfma_f32_16x16x32_f16(af, bf, acc[s], 0, 0, 0);
        }
    }

    // cross-wave K-reduce + epilogue, one 16-row subtile at a time
    const float* ihp = ihd + p * NN;
    for (int s = 0; s < 8; ++s) {
        __syncthreads();
        *(f32x4*)&red[wv][lane * 4] = acc[s];
        __syncthreads();
        if (tid < 256) {
            int ln = tid >> 2, rg = tid & 3;
            int n = ln & 15, mloc = (ln >> 4) * 4 + rg;   // C/D: col=lane&15, row=quad*4+reg
            int r = m0 + s * 16 + mloc;
            float sum = 0.f;
#pragma unroll
            for (int w = 0; w < 16; ++w) sum += red[w][tid];
            float cv = (float)Bt[((size_t)p * 16 + n) * NN + r];
            float o = 0.5f * cv + ihp[r] * sum;
            Ct[((size_t)p * 16 + n) * NN + r] = (_Float16)o;
            if (lvl) lvl[(((size_t)p * 5 + t) * 16 + n) * NN + r] = o;
        }
    }
}

// ---- build UT fp16 [p][16][2048]: rows 0-11 = |psi_0..3 X|, 12-15 = 0 ----
__global__ __launch_bounds__(256) void buildU_k(const float* __restrict__ Xs,
                                                const float* __restrict__ LT1,
                                                _Float16* __restrict__ UT) {
    int p = blockIdx.y;
    int m = blockIdx.x * 256 + threadIdx.x;
    const float* lp = LT1 + (size_t)p * 5 * 16 * NN;
    float4 xr = ((const float4*)Xs)[p * NN + m];
    float prev[3] = {xr.x, xr.y, xr.z};
    _Float16* ut = UT + (size_t)p * 16 * NN + m;
#pragma unroll
    for (int jw = 0; jw < 4; ++jw) {
#pragma unroll
        for (int c = 0; c < 3; ++c) {
            float nx = lp[((size_t)jw * 16 + c) * NN + m];
            ut[(3 * jw + c) * NN] = (_Float16)fabsf(prev[c] - nx);
            prev[c] = nx;
        }
    }
#pragma unroll
    for (int n = 12; n < 16; ++n) ut[n * NN] = (_Float16)0.f;
}

// ---- final mean over N of 48 features (levels [p][t][n][m]) ----
__global__ __launch_bounds__(64) void reduce_k(const float* __restrict__ Xs,
                                               const float* __restrict__ LT1,
                                               const float* __restrict__ LT2,
                                               float* __restrict__ out) {
    int f = blockIdx.x, p = blockIdx.y, lane = threadIdx.x;
    const float* l1 = LT1 + (size_t)p * 5 * 16 * NN;
    const float* l2 = LT2 + (size_t)p * 5 * 16 * NN;
    float s = 0.f;
    for (int m = lane; m < NN; m += 64) {
        float v;
        if (f < 3) {
            v = l1[((size_t)4 * 16 + f) * NN + m];
        } else if (f < 18) {
            int j = (f - 3) / 3, c = (f - 3) % 3;
            float a = (j == 0) ? Xs[((size_t)p * NN + m) * 4 + c]
                               : l1[((size_t)(j - 1) * 16 + c) * NN + m];
            float b = l1[((size_t)j * 16 + c) * NN + m];
            v = fabsf(a - b);
        } else {
            int gg = f - 18, j2, uc;
            if (gg < 3)       { j2 = 1; uc = gg; }
            else if (gg < 9)  { j2 = 2; uc = gg - 3; }
            else if (gg < 18) { j2 = 3; uc = gg - 9; }
            else              { j2 = 4; uc = gg - 18; }
            v = fabsf(l2[((size_t)(j2 - 1) * 16 + uc) * NN + m]
                    - l2[((size_t)j2 * 16 + uc) * NN + m]);
        }
        s += v;
    }
#pragma unroll
    for (int off = 32; off > 0; off >>= 1) s += __shfl_down(s, off, 64);
    if (lane == 0) out[p * 48 + f] = s * (1.0f / NN);
}

extern "C" void kernel_launch(void* const* d_in, const int* in_sizes, int n_in,
                              void* d_out, int out_size, void* d_ws, size_t ws_size,
                              hipStream_t stream) {
    const float* pc     = (const float*)d_in[0];
    const float* alphas = (const float*)d_in[1];
    float* outp = (float*)d_out;

    char* base = (char*)d_ws;
    size_t off = 0;
    auto carve = [&](size_t bytes) -> void* {
        void* r = base + off;
        off = (off + bytes + 255) & ~(size_t)255;
        return r;
    };
    float*     Xs  = (float*)carve((size_t)NPAIR * NN * 4 * sizeof(float));
    float*     ihd = (float*)carve((size_t)NPAIR * NN * sizeof(float));
    _Float16*  XT  = (_Float16*)carve((size_t)NPAIR * 16 * NN * 2);
    _Float16*  UT  = (_Float16*)carve((size_t)NPAIR * 16 * NN * 2);
    _Float16*  pA  = (_Float16*)carve((size_t)NPAIR * 16 * NN * 2);
    _Float16*  pB  = (_Float16*)carve((size_t)NPAIR * 16 * NN * 2);
    float*     LT1 = (float*)carve((size_t)NPAIR * 5 * 16 * NN * sizeof(float));
    float*     LT2 = (float*)carve((size_t)NPAIR * 5 * 16 * NN * sizeof(float));

    dim3 gridA(NN / 128, NPAIR);   // 16 x 16 = 256 blocks (1/CU)

    init_k<<<dim3((NPAIR * NN) / 256), 256, 0, stream>>>(pc, alphas, Xs, XT);
    deg_k<<<gridA, 1024, 0, stream>>>(Xs, ihd);

    // bank 1: B = XT
    {
        const _Float16* cur = XT;
        int slot = 0;
        for (int step = 1; step <= 16; ++step) {
            bool sv = (step == 1 || step == 2 || step == 4 || step == 8 || step == 16);
            _Float16* o = (cur == pA) ? pB : pA;
            fused_apply_k<<<gridA, 1024, 0, stream>>>(Xs, ihd, cur, o,
                                                      sv ? LT1 : nullptr, slot);
            if (sv) ++slot;
            cur = o;
        }
    }

    buildU_k<<<dim3(NN / 256, NPAIR), 256, 0, stream>>>(Xs, LT1, UT);

    // bank 2: B = UT
    {
        const _Float16* cur = UT;
        int slot = 0;
        for (int step = 1; step <= 16; ++step) {
            bool sv = (step == 1 || step == 2 || step == 4 || step == 8 || step == 16);
            _Float16* o = (cur == pA) ? pB : pA;
            fused_apply_k<<<gridA, 1024, 0, stream>>>(Xs, ihd, cur, o,
                                                      sv ? LT2 : nullptr, slot);
            if (sv) ++slot;
            cur = o;
        }
    }

    reduce_k<<<dim3(48, NPAIR), 64, 0, stream>>>(Xs, LT1, LT2, outp);
}

// Round 8
// 688.290 us; speedup vs baseline: 1.5970x; 1.3695x over previous
//
#include <hip/hip_runtime.h>
#include <hip/hip_bf16.h>

// PointCloudNetPersistencePrediction — round 7b: compile fix of round 7.
// (cvt_pkrtz returns __fp16x2, not _Float16x2 — union through __fp16.)
// R6 post-mortem: applies ~27us (pred 10-14). Causes: 10 instr/eval (scalar
// f16 cvts, unhoisted C2F), 16 syncthreads/epilogue, 4 waves/SIMD, deg_k 45us.
// Fixes: xi pre-scaled by C2F + pkrtz pack (6.5 instr/eval); single-pass
// 2-sync epilogue; M=64 blocks -> grid 512 = 2 blocks/CU @ launch_bounds(1024,8);
// XT col3=ones -> apply#1's MFMA col3 = deg (P@1=1 keeps it exact after).

#define NN 2048
#define NPAIR 16

typedef _Float16 half8 __attribute__((ext_vector_type(8)));
typedef __fp16   fp16x2 __attribute__((ext_vector_type(2)));
typedef float f32x4 __attribute__((ext_vector_type(4)));

#define C2F 0.28853900817779268f   //  0.2 * log2(e)
#define CWF -0.14426950408889634f  // -0.1 * log2(e)
#define L2T -3.3219280948873623f   //  log2(0.1): w<0.1 <=> arg<L2T

// ---- init: Xs fp32 [p][i][{x,y,z,q}]; XT fp16 [p][16][2048], row3 = ones ----
__global__ __launch_bounds__(256) void init_k(const float* __restrict__ pc,
                                              const float* __restrict__ alphas,
                                              float* __restrict__ Xs,
                                              _Float16* __restrict__ XT) {
    int gid = blockIdx.x * 256 + threadIdx.x;
    if (gid >= NPAIR * NN) return;
    int p = gid >> 11, i = gid & (NN - 1);
    int b = p >> 2, k = p & 3;
    const float* pcr = pc + ((size_t)b * NN + i) * 3;
    const float* al  = alphas + k * 3;
    float x = pcr[0] * al[0], y = pcr[1] * al[1], z = pcr[2] * al[2];
    float4 o; o.x = x; o.y = y; o.z = z; o.w = CWF * (x * x + y * y + z * z);
    ((float4*)Xs)[gid] = o;
    _Float16* xt = XT + (size_t)p * 16 * NN + i;
    xt[0 * NN] = (_Float16)x;
    xt[1 * NN] = (_Float16)y;
    xt[2 * NN] = (_Float16)z;
    xt[3 * NN] = (_Float16)1.0f;          // ones column -> deg via MFMA
#pragma unroll
    for (int n = 4; n < 16; ++n) xt[n * NN] = (_Float16)0.f;
}

// xi.xyz pre-scaled by C2F; xj raw. w = exp2(qi+qj+dot), 0 if arg<log2(0.1).
__device__ __forceinline__ float evalw(float4 xi, float4 xj) {
    float t = xi.w + xj.w;
    t = fmaf(xi.x, xj.x, t);
    t = fmaf(xi.y, xj.y, t);
    t = fmaf(xi.z, xj.z, t);
    float w = __builtin_amdgcn_exp2f(t);
    return (t < L2T) ? 0.f : w;
}

// ---- fused apply: Ct = f16(0.5*Bt + ihd (x) (W@Bt^T)^T), W recomputed ----
// block = 1024 thr = 16 waves = (mg 2 Msub x kg 8 Kchunks); M=64 rows/block.
// Lane: 2 s-subtiles (16 rows), K-chunk 256. Grid (32,16)=512 -> 2 blocks/CU.
template<bool FIRST>
__global__ __launch_bounds__(1024, 8) void fused_apply_k(const float* __restrict__ Xs,
                                                         float* __restrict__ ihd,
                                                         const _Float16* __restrict__ Bt,
                                                         _Float16* __restrict__ Ct,
                                                         float* __restrict__ lvl,
                                                         int t) {
    __shared__ __align__(16) float smem[8192];     // 32 KB: Xlds, then red
    const int tid  = threadIdx.x;
    const int lane = tid & 63;
    const int wv   = tid >> 6;
    const int p    = blockIdx.y;
    const int m0   = blockIdx.x * 64;
    const int idx16 = lane & 15, quad = lane >> 4;
    const int mg = wv & 1, kg = wv >> 1;

    // stage whole pair X into LDS (2048 float4)
    {
        const float4* src = (const float4*)(Xs + (size_t)p * NN * 4);
        float4* dst = (float4*)smem;
        dst[tid]        = src[tid];
        dst[tid + 1024] = src[tid + 1024];
    }
    __syncthreads();

    float4 xi[2];
#pragma unroll
    for (int s = 0; s < 2; ++s) {
        float4 v = ((const float4*)smem)[m0 + mg * 32 + s * 16 + idx16];
        xi[s].x = C2F * v.x; xi[s].y = C2F * v.y; xi[s].z = C2F * v.z; xi[s].w = v.w;
    }

    const _Float16* bp = Bt + ((size_t)p * 16 + idx16) * NN + kg * 256 + quad * 8;
    f32x4 acc[2] = {{0.f,0.f,0.f,0.f},{0.f,0.f,0.f,0.f}};

    for (int kc = 0; kc < 8; ++kc) {
        const int kb = kg * 256 + kc * 32 + quad * 8;
        half8 bf = *(const half8*)(bp + kc * 32);
        union { fp16x2 h2[4]; half8 h8; } af0, af1;
#pragma unroll
        for (int jp = 0; jp < 4; ++jp) {
            float4 xj0 = ((const float4*)smem)[kb + 2 * jp];
            float4 xj1 = ((const float4*)smem)[kb + 2 * jp + 1];
            float w00 = evalw(xi[0], xj0), w01 = evalw(xi[0], xj1);
            float w10 = evalw(xi[1], xj0), w11 = evalw(xi[1], xj1);
            af0.h2[jp] = __builtin_amdgcn_cvt_pkrtz(w00, w01);
            af1.h2[jp] = __builtin_amdgcn_cvt_pkrtz(w10, w11);
        }
        acc[0] = __builtin_amdgcn_mfma_f32_16x16x32_f16(af0.h8, bf, acc[0], 0, 0, 0);
        acc[1] = __builtin_amdgcn_mfma_f32_16x16x32_f16(af1.h8, bf, acc[1], 0, 0, 0);
    }

    // cross-wave K-reduce: red[kg 8][ms 4][256] aliased over Xlds
    __syncthreads();
#pragma unroll
    for (int s = 0; s < 2; ++s)
        *(f32x4*)&smem[(kg * 4 + mg * 2 + s) * 256 + lane * 4] = acc[s];
    __syncthreads();

    // one output per thread: n = tid&15, rloc = tid>>4
    const int n = tid & 15, rloc = tid >> 4;
    const int ms = rloc >> 4, mloc = rloc & 15;
    const int base = ms * 256 + (mloc >> 2) * 64 + (mloc & 3);
    float sum = 0.f;
#pragma unroll
    for (int g = 0; g < 8; ++g) sum += smem[g * 1024 + base + n * 4];
    const int row = m0 + rloc;
    float ih;
    if (FIRST) {
        float deg = 0.f;
#pragma unroll
        for (int g = 0; g < 8; ++g) deg += smem[g * 1024 + base + 12];  // col 3
        ih = 0.5f / deg;
        if (n == 3) ihd[p * NN + row] = ih;
    } else {
        ih = ihd[p * NN + row];
    }
    float cv = (float)Bt[((size_t)p * 16 + n) * NN + row];
    float o = 0.5f * cv + ih * sum;
    Ct[((size_t)p * 16 + n) * NN + row] = (_Float16)o;
    if (lvl) lvl[(((size_t)p * 5 + t) * 16 + n) * NN + row] = o;
}

// ---- build UT fp16 [p][16][2048]: rows 0-11 = |psi_0..3 X|, 12-15 = 0 ----
__global__ __launch_bounds__(256) void buildU_k(const float* __restrict__ Xs,
                                                const float* __restrict__ LT1,
                                                _Float16* __restrict__ UT) {
    int p = blockIdx.y;
    int m = blockIdx.x * 256 + threadIdx.x;
    const float* lp = LT1 + (size_t)p * 5 * 16 * NN;
    float4 xr = ((const float4*)Xs)[p * NN + m];
    float prev[3] = {xr.x, xr.y, xr.z};
    _Float16* ut = UT + (size_t)p * 16 * NN + m;
#pragma unroll
    for (int jw = 0; jw < 4; ++jw) {
#pragma unroll
        for (int c = 0; c < 3; ++c) {
            float nx = lp[((size_t)jw * 16 + c) * NN + m];
            ut[(3 * jw + c) * NN] = (_Float16)fabsf(prev[c] - nx);
            prev[c] = nx;
        }
    }
#pragma unroll
    for (int n = 12; n < 16; ++n) ut[n * NN] = (_Float16)0.f;
}

// ---- final mean over N of 48 features (levels [p][t][n][m]) ----
__global__ __launch_bounds__(64) void reduce_k(const float* __restrict__ Xs,
                                               const float* __restrict__ LT1,
                                               const float* __restrict__ LT2,
                                               float* __restrict__ out) {
    int f = blockIdx.x, p = blockIdx.y, lane = threadIdx.x;
    const float* l1 = LT1 + (size_t)p * 5 * 16 * NN;
    const float* l2 = LT2 + (size_t)p * 5 * 16 * NN;
    float s = 0.f;
    for (int m = lane; m < NN; m += 64) {
        float v;
        if (f < 3) {
            v = l1[((size_t)4 * 16 + f) * NN + m];
        } else if (f < 18) {
            int j = (f - 3) / 3, c = (f - 3) % 3;
            float a = (j == 0) ? Xs[((size_t)p * NN + m) * 4 + c]
                               : l1[((size_t)(j - 1) * 16 + c) * NN + m];
            float b = l1[((size_t)j * 16 + c) * NN + m];
            v = fabsf(a - b);
        } else {
            int gg = f - 18, j2, uc;
            if (gg < 3)       { j2 = 1; uc = gg; }
            else if (gg < 9)  { j2 = 2; uc = gg - 3; }
            else if (gg < 18) { j2 = 3; uc = gg - 9; }
            else              { j2 = 4; uc = gg - 18; }
            v = fabsf(l2[((size_t)(j2 - 1) * 16 + uc) * NN + m]
                    - l2[((size_t)j2 * 16 + uc) * NN + m]);
        }
        s += v;
    }
#pragma unroll
    for (int off = 32; off > 0; off >>= 1) s += __shfl_down(s, off, 64);
    if (lane == 0) out[p * 48 + f] = s * (1.0f / NN);
}

extern "C" void kernel_launch(void* const* d_in, const int* in_sizes, int n_in,
                              void* d_out, int out_size, void* d_ws, size_t ws_size,
                              hipStream_t stream) {
    const float* pc     = (const float*)d_in[0];
    const float* alphas = (const float*)d_in[1];
    float* outp = (float*)d_out;

    char* base = (char*)d_ws;
    size_t off = 0;
    auto carve = [&](size_t bytes) -> void* {
        void* r = base + off;
        off = (off + bytes + 255) & ~(size_t)255;
        return r;
    };
    float*     Xs  = (float*)carve((size_t)NPAIR * NN * 4 * sizeof(float));
    float*     ihd = (float*)carve((size_t)NPAIR * NN * sizeof(float));
    _Float16*  XT  = (_Float16*)carve((size_t)NPAIR * 16 * NN * 2);
    _Float16*  UT  = (_Float16*)carve((size_t)NPAIR * 16 * NN * 2);
    _Float16*  pA  = (_Float16*)carve((size_t)NPAIR * 16 * NN * 2);
    _Float16*  pB  = (_Float16*)carve((size_t)NPAIR * 16 * NN * 2);
    float*     LT1 = (float*)carve((size_t)NPAIR * 5 * 16 * NN * sizeof(float));
    float*     LT2 = (float*)carve((size_t)NPAIR * 5 * 16 * NN * sizeof(float));

    dim3 gridA(NN / 64, NPAIR);   // 32 x 16 = 512 blocks -> 2 blocks/CU

    init_k<<<dim3((NPAIR * NN) / 256), 256, 0, stream>>>(pc, alphas, Xs, XT);

    // bank 1: B = XT (col3 = ones -> apply#1 computes deg/ihd itself)
    {
        const _Float16* cur = XT;
        int slot = 0;
        for (int step = 1; step <= 16; ++step) {
            bool sv = (step == 1 || step == 2 || step == 4 || step == 8 || step == 16);
            _Float16* o = (cur == pA) ? pB : pA;
            float* lv = sv ? LT1 : nullptr;
            if (step == 1)
                fused_apply_k<true><<<gridA, 1024, 0, stream>>>(Xs, ihd, cur, o, lv, slot);
            else
                fused_apply_k<false><<<gridA, 1024, 0, stream>>>(Xs, ihd, cur, o, lv, slot);
            if (sv) ++slot;
            cur = o;
        }
    }

    buildU_k<<<dim3(NN / 256, NPAIR), 256, 0, stream>>>(Xs, LT1, UT);

    // bank 2: B = UT
    {
        const _Float16* cur = UT;
        int slot = 0;
        for (int step = 1; step <= 16; ++step) {
            bool sv = (step == 1 || step == 2 || step == 4 || step == 8 || step == 16);
            _Float16* o = (cur == pA) ? pB : pA;
            fused_apply_k<false><<<gridA, 1024, 0, stream>>>(Xs, ihd, cur, o,
                                                             sv ? LT2 : nullptr, slot);
            if (sv) ++slot;
            cur = o;
        }
    }

    reduce_k<<<dim3(48, NPAIR), 64, 0, stream>>>(Xs, LT1, LT2, outp);
}

// Round 9
// 674.285 us; speedup vs baseline: 1.6301x; 1.0208x over previous
//
#include <hip/hip_runtime.h>
#include <hip/hip_bf16.h>

// PointCloudNetPersistencePrediction — round 9: halve LDS-read demand.
// R8 post-mortem: applies 18.5us, LDS-pipe-bound (per CU: ~10.2us of
// ds_read_b128 vs 5.5us VALU; 8 xj reads per kc fed only 2 m-subtiles).
// Fix: 4 m-subtiles per lane (xi[4]/acc[4]) -> same xj reads feed 2x evals.
// Block 512 thr = 8 K-split waves, M=64, red LDS 32KB aliased over X stage,
// launch_bounds(512,4) => VGPR<=128, no hot-loop spill.

#define NN 2048
#define NPAIR 16

typedef _Float16 half8 __attribute__((ext_vector_type(8)));
typedef __fp16   fp16x2 __attribute__((ext_vector_type(2)));
typedef float f32x4 __attribute__((ext_vector_type(4)));

#define C2F 0.28853900817779268f   //  0.2 * log2(e)
#define CWF -0.14426950408889634f  // -0.1 * log2(e)
#define L2T -3.3219280948873623f   //  log2(0.1): w<0.1 <=> arg<L2T

// ---- init: Xs fp32 [p][i][{x,y,z,q}]; XT fp16 [p][16][2048], row3 = ones ----
__global__ __launch_bounds__(256) void init_k(const float* __restrict__ pc,
                                              const float* __restrict__ alphas,
                                              float* __restrict__ Xs,
                                              _Float16* __restrict__ XT) {
    int gid = blockIdx.x * 256 + threadIdx.x;
    if (gid >= NPAIR * NN) return;
    int p = gid >> 11, i = gid & (NN - 1);
    int b = p >> 2, k = p & 3;
    const float* pcr = pc + ((size_t)b * NN + i) * 3;
    const float* al  = alphas + k * 3;
    float x = pcr[0] * al[0], y = pcr[1] * al[1], z = pcr[2] * al[2];
    float4 o; o.x = x; o.y = y; o.z = z; o.w = CWF * (x * x + y * y + z * z);
    ((float4*)Xs)[gid] = o;
    _Float16* xt = XT + (size_t)p * 16 * NN + i;
    xt[0 * NN] = (_Float16)x;
    xt[1 * NN] = (_Float16)y;
    xt[2 * NN] = (_Float16)z;
    xt[3 * NN] = (_Float16)1.0f;          // ones column -> deg via MFMA
#pragma unroll
    for (int n = 4; n < 16; ++n) xt[n * NN] = (_Float16)0.f;
}

// xi.xyz pre-scaled by C2F; xj raw. w = exp2(qi+qj+dot), 0 if arg<log2(0.1).
__device__ __forceinline__ float evalw(float4 xi, float4 xj) {
    float t = xi.w + xj.w;
    t = fmaf(xi.x, xj.x, t);
    t = fmaf(xi.y, xj.y, t);
    t = fmaf(xi.z, xj.z, t);
    float w = __builtin_amdgcn_exp2f(t);
    return (t < L2T) ? 0.f : w;
}

// ---- fused apply: Ct = f16(0.5*Bt + ihd (x) (W@Bt^T)^T), W recomputed ----
// block = 512 thr = 8 waves, each wave = K-chunk 256; lane owns 4 m-subtiles
// (M=64 rows/block). Grid (32,16)=512 blocks. Red LDS aliases X stage (32KB).
template<bool FIRST>
__global__ __launch_bounds__(512, 4) void fused_apply_k(const float* __restrict__ Xs,
                                                        float* __restrict__ ihd,
                                                        const _Float16* __restrict__ Bt,
                                                        _Float16* __restrict__ Ct,
                                                        float* __restrict__ lvl,
                                                        int t) {
    __shared__ __align__(16) float smem[8192];     // 32 KB: X stage, then red
    const int tid  = threadIdx.x;
    const int lane = tid & 63;
    const int wv   = tid >> 6;                     // K-group 0..7
    const int p    = blockIdx.y;
    const int m0   = blockIdx.x * 64;
    const int idx16 = lane & 15, quad = lane >> 4;

    // stage whole pair X into LDS (2048 float4, 4 per thread)
    {
        const float4* src = (const float4*)(Xs + (size_t)p * NN * 4);
        float4* dst = (float4*)smem;
        dst[tid]        = src[tid];
        dst[tid + 512]  = src[tid + 512];
        dst[tid + 1024] = src[tid + 1024];
        dst[tid + 1536] = src[tid + 1536];
    }
    __syncthreads();

    float4 xi[4];
#pragma unroll
    for (int s = 0; s < 4; ++s) {
        float4 v = ((const float4*)smem)[m0 + s * 16 + idx16];
        xi[s].x = C2F * v.x; xi[s].y = C2F * v.y; xi[s].z = C2F * v.z; xi[s].w = v.w;
    }

    const _Float16* bp = Bt + ((size_t)p * 16 + idx16) * NN + wv * 256 + quad * 8;
    f32x4 acc[4] = {{0.f,0.f,0.f,0.f},{0.f,0.f,0.f,0.f},
                    {0.f,0.f,0.f,0.f},{0.f,0.f,0.f,0.f}};

    for (int kc = 0; kc < 8; ++kc) {
        const int kb = wv * 256 + kc * 32 + quad * 8;
        half8 bf = *(const half8*)(bp + kc * 32);
        union { fp16x2 h2[4]; half8 h8; } af[4];
#pragma unroll
        for (int jp = 0; jp < 4; ++jp) {
            float4 xj0 = ((const float4*)smem)[kb + 2 * jp];
            float4 xj1 = ((const float4*)smem)[kb + 2 * jp + 1];
#pragma unroll
            for (int s = 0; s < 4; ++s)
                af[s].h2[jp] = __builtin_amdgcn_cvt_pkrtz(evalw(xi[s], xj0),
                                                          evalw(xi[s], xj1));
        }
#pragma unroll
        for (int s = 0; s < 4; ++s)
            acc[s] = __builtin_amdgcn_mfma_f32_16x16x32_f16(af[s].h8, bf, acc[s], 0, 0, 0);
    }

    // cross-wave K-reduce: red[kg 8][s 4][256] aliased over X stage
    __syncthreads();
#pragma unroll
    for (int s = 0; s < 4; ++s)
        *(f32x4*)&smem[wv * 1024 + s * 256 + lane * 4] = acc[s];
    __syncthreads();

    // 2 outputs/thread: o -> n = o&15, rloc = o>>4 (s = rloc>>4, mloc = rloc&15)
    const float* ihp = ihd + p * NN;
#pragma unroll
    for (int oo = 0; oo < 2; ++oo) {
        const int o = tid + oo * 512;
        const int n = o & 15, rloc = o >> 4;
        const int s = rloc >> 4, mloc = rloc & 15;
        const int base = s * 256 + (mloc >> 2) * 64 + (mloc & 3);
        float sum = 0.f;
#pragma unroll
        for (int g = 0; g < 8; ++g) sum += smem[g * 1024 + base + n * 4];
        const int row = m0 + rloc;
        float ih;
        if (FIRST) {
            float deg = 0.f;
#pragma unroll
            for (int g = 0; g < 8; ++g) deg += smem[g * 1024 + base + 12];  // col 3
            ih = 0.5f / deg;
            if (n == 3) ihd[p * NN + row] = ih;
        } else {
            ih = ihp[row];
        }
        float cv = (float)Bt[((size_t)p * 16 + n) * NN + row];
        float out = 0.5f * cv + ih * sum;
        Ct[((size_t)p * 16 + n) * NN + row] = (_Float16)out;
        if (lvl) lvl[(((size_t)p * 5 + t) * 16 + n) * NN + row] = out;
    }
}

// ---- build UT fp16 [p][16][2048]: rows 0-11 = |psi_0..3 X|, 12-15 = 0 ----
__global__ __launch_bounds__(256) void buildU_k(const float* __restrict__ Xs,
                                                const float* __restrict__ LT1,
                                                _Float16* __restrict__ UT) {
    int p = blockIdx.y;
    int m = blockIdx.x * 256 + threadIdx.x;
    const float* lp = LT1 + (size_t)p * 5 * 16 * NN;
    float4 xr = ((const float4*)Xs)[p * NN + m];
    float prev[3] = {xr.x, xr.y, xr.z};
    _Float16* ut = UT + (size_t)p * 16 * NN + m;
#pragma unroll
    for (int jw = 0; jw < 4; ++jw) {
#pragma unroll
        for (int c = 0; c < 3; ++c) {
            float nx = lp[((size_t)jw * 16 + c) * NN + m];
            ut[(3 * jw + c) * NN] = (_Float16)fabsf(prev[c] - nx);
            prev[c] = nx;
        }
    }
#pragma unroll
    for (int n = 12; n < 16; ++n) ut[n * NN] = (_Float16)0.f;
}

// ---- final mean over N of 48 features (levels [p][t][n][m]) ----
__global__ __launch_bounds__(64) void reduce_k(const float* __restrict__ Xs,
                                               const float* __restrict__ LT1,
                                               const float* __restrict__ LT2,
                                               float* __restrict__ out) {
    int f = blockIdx.x, p = blockIdx.y, lane = threadIdx.x;
    const float* l1 = LT1 + (size_t)p * 5 * 16 * NN;
    const float* l2 = LT2 + (size_t)p * 5 * 16 * NN;
    float s = 0.f;
    for (int m = lane; m < NN; m += 64) {
        float v;
        if (f < 3) {
            v = l1[((size_t)4 * 16 + f) * NN + m];
        } else if (f < 18) {
            int j = (f - 3) / 3, c = (f - 3) % 3;
            float a = (j == 0) ? Xs[((size_t)p * NN + m) * 4 + c]
                               : l1[((size_t)(j - 1) * 16 + c) * NN + m];
            float b = l1[((size_t)j * 16 + c) * NN + m];
            v = fabsf(a - b);
        } else {
            int gg = f - 18, j2, uc;
            if (gg < 3)       { j2 = 1; uc = gg; }
            else if (gg < 9)  { j2 = 2; uc = gg - 3; }
            else if (gg < 18) { j2 = 3; uc = gg - 9; }
            else              { j2 = 4; uc = gg - 18; }
            v = fabsf(l2[((size_t)(j2 - 1) * 16 + uc) * NN + m]
                    - l2[((size_t)j2 * 16 + uc) * NN + m]);
        }
        s += v;
    }
#pragma unroll
    for (int off = 32; off > 0; off >>= 1) s += __shfl_down(s, off, 64);
    if (lane == 0) out[p * 48 + f] = s * (1.0f / NN);
}

extern "C" void kernel_launch(void* const* d_in, const int* in_sizes, int n_in,
                              void* d_out, int out_size, void* d_ws, size_t ws_size,
                              hipStream_t stream) {
    const float* pc     = (const float*)d_in[0];
    const float* alphas = (const float*)d_in[1];
    float* outp = (float*)d_out;

    char* base = (char*)d_ws;
    size_t off = 0;
    auto carve = [&](size_t bytes) -> void* {
        void* r = base + off;
        off = (off + bytes + 255) & ~(size_t)255;
        return r;
    };
    float*     Xs  = (float*)carve((size_t)NPAIR * NN * 4 * sizeof(float));
    float*     ihd = (float*)carve((size_t)NPAIR * NN * sizeof(float));
    _Float16*  XT  = (_Float16*)carve((size_t)NPAIR * 16 * NN * 2);
    _Float16*  UT  = (_Float16*)carve((size_t)NPAIR * 16 * NN * 2);
    _Float16*  pA  = (_Float16*)carve((size_t)NPAIR * 16 * NN * 2);
    _Float16*  pB  = (_Float16*)carve((size_t)NPAIR * 16 * NN * 2);
    float*     LT1 = (float*)carve((size_t)NPAIR * 5 * 16 * NN * sizeof(float));
    float*     LT2 = (float*)carve((size_t)NPAIR * 5 * 16 * NN * sizeof(float));

    dim3 gridA(NN / 64, NPAIR);   // 32 x 16 = 512 blocks

    init_k<<<dim3((NPAIR * NN) / 256), 256, 0, stream>>>(pc, alphas, Xs, XT);

    // bank 1: B = XT (col3 = ones -> apply#1 computes deg/ihd itself)
    {
        const _Float16* cur = XT;
        int slot = 0;
        for (int step = 1; step <= 16; ++step) {
            bool sv = (step == 1 || step == 2 || step == 4 || step == 8 || step == 16);
            _Float16* o = (cur == pA) ? pB : pA;
            float* lv = sv ? LT1 : nullptr;
            if (step == 1)
                fused_apply_k<true><<<gridA, 512, 0, stream>>>(Xs, ihd, cur, o, lv, slot);
            else
                fused_apply_k<false><<<gridA, 512, 0, stream>>>(Xs, ihd, cur, o, lv, slot);
            if (sv) ++slot;
            cur = o;
        }
    }

    buildU_k<<<dim3(NN / 256, NPAIR), 256, 0, stream>>>(Xs, LT1, UT);

    // bank 2: B = UT
    {
        const _Float16* cur = UT;
        int slot = 0;
        for (int step = 1; step <= 16; ++step) {
            bool sv = (step == 1 || step == 2 || step == 4 || step == 8 || step == 16);
            _Float16* o = (cur == pA) ? pB : pA;
            fused_apply_k<false><<<gridA, 512, 0, stream>>>(Xs, ihd, cur, o,
                                                            sv ? LT2 : nullptr, slot);
            if (sv) ++slot;
            cur = o;
        }
    }

    reduce_k<<<dim3(48, NPAIR), 64, 0, stream>>>(Xs, LT1, LT2, outp);
}